// Round 1
// baseline (678.932 us; speedup 1.0000x reference)
//
#include <hip/hip_runtime.h>
#include <hip/hip_bf16.h>

// InteractingLayer: B=16384, F=40, E=64, H=4, D=32, OUT=128
// One block (256 thr, 4 waves) per batch element. Wave w: projection w (Q,K,V,R),
// then head w attention. All matmuls via mfma_f32_16x16x32_bf16.

#define F_DIM 40
#define E_DIM 64
#define O_DIM 128

typedef __bf16 bf16x8 __attribute__((ext_vector_type(8)));
typedef float  f32x4  __attribute__((ext_vector_type(4)));

// ---- LDS layout (ushort/bf16 element offsets) ----
// Q  [40][136]  @ 0       (rows 40..47 read-spill into K: garbage OK, masked)
// K  [40][136]  @ 5440    (rows 40..47 read-spill into Vt: garbage OK, masked)
// Vt [128][72]  @ 10880   (cols 48..63 zeroed; cols 40..47 = bias, finite)
// R  [40][136]  @ 20096
// U  @ 25536: xb [48][72] (phase A-B)  OVERLAPS  P_w [40][72] x4 (+576 tail for
//             P3 row-spill reads). P stores predicated f<40; spill reads are
//             A-operand rows -> NaN contained to discarded output rows.
#define QO 0
#define KO 5440
#define VO 10880
#define RO 20096
#define UO 25536
#define PSZ 2880
#define TOT 37632   // 75264 bytes -> 2 blocks/CU

static __device__ __forceinline__ unsigned short f2bf(float f) {
  unsigned u = __builtin_bit_cast(unsigned, f);
  u += 0x7FFFu + ((u >> 16) & 1u);          // RNE
  return (unsigned short)(u >> 16);
}
static __device__ __forceinline__ float bf2f(unsigned short h) {
  unsigned u = ((unsigned)h) << 16;
  return __builtin_bit_cast(float, u);
}
static __device__ __forceinline__ unsigned pk2(float a, float b) {
  return (unsigned)f2bf(a) | ((unsigned)f2bf(b) << 16);
}
union LdsVec { uint2 u2[2]; bf16x8 v; };
static __device__ __forceinline__ bf16x8 lds_ld8(const unsigned short* p) {
  LdsVec t;
  t.u2[0] = *reinterpret_cast<const uint2*>(p);
  t.u2[1] = *reinterpret_cast<const uint2*>(p + 4);
  return t.v;
}
static __device__ __forceinline__ f32x4 mfma16(bf16x8 a, bf16x8 b, f32x4 c) {
  return __builtin_amdgcn_mfma_f32_16x16x32_bf16(a, b, c, 0, 0, 0);
}

#if __has_builtin(__builtin_amdgcn_exp2f)
#define EXP2F __builtin_amdgcn_exp2f
#else
#define EXP2F exp2f
#endif
#if __has_builtin(__builtin_amdgcn_rcpf)
#define RCPF __builtin_amdgcn_rcpf
#else
#define RCPF(x) (1.0f / (x))
#endif

__global__ void convert_weights(const float* __restrict__ Wq, const float* __restrict__ Wk,
                                const float* __restrict__ Wv, const float* __restrict__ Wr,
                                unsigned short* __restrict__ ws) {
  int i = blockIdx.x * 256 + threadIdx.x;   // 0..32767
  const float* src = (i < 8192) ? Wq : (i < 16384) ? Wk : (i < 24576) ? Wv : Wr;
  ws[i] = f2bf(src[i & 8191]);
}

__global__ __launch_bounds__(256, 2) void interact_kernel(
    const float* __restrict__ x, const unsigned short* __restrict__ wbf,
    const float* __restrict__ bq, const float* __restrict__ bk,
    const float* __restrict__ bv, const float* __restrict__ br,
    float* __restrict__ out) {
  __shared__ __align__(16) unsigned short sm[TOT];
  const int t = threadIdx.x;
  const int w = t >> 6;        // wave 0..3
  const int l = t & 63;
  const int c = l & 15;        // MFMA col / m-lane
  const int q = l >> 4;        // quad
  const int b = blockIdx.x;

  // ---------- Phase A: stage x -> LDS bf16; zero pads ----------
  const float* xp = x + (size_t)b * (F_DIM * E_DIM);
  for (int i = t; i < 640; i += 256) {                       // 640 float4 = 40x64
    float4 v4 = reinterpret_cast<const float4*>(xp)[i];
    int f = i >> 4, e4 = (i & 15) << 2;
    uint2 pk; pk.x = pk2(v4.x, v4.y); pk.y = pk2(v4.z, v4.w);
    *reinterpret_cast<uint2*>(sm + UO + f * 72 + e4) = pk;
  }
  {
    uint2 z; z.x = 0; z.y = 0;
    for (int i = t; i < 144; i += 256)                       // xb rows 40..47 = 0
      reinterpret_cast<uint2*>(sm + UO + 40 * 72)[i] = z;
    for (int i = t; i < 512; i += 256) {                     // Vt[:, 48..63] = 0
      int d = i >> 2, j = i & 3;
      *reinterpret_cast<uint2*>(sm + VO + d * 72 + 48 + 4 * j) = z;
    }
  }
  __syncthreads();

  // ---------- Phase B: projections ----------
  const unsigned short* Wg = wbf + w * 8192;                 // this wave's W, bf16 [128][64]
  const float* bias = (w == 0) ? bq : (w == 1) ? bk : (w == 2) ? bv : br;
  f32x4 z4 = {0.f, 0.f, 0.f, 0.f};

  if (w != 2) {
    // D[o][f] = sum_e W[o][e] * x[f][e]   (A = W rows, B = x rows)
    bf16x8 bx[3][2];
#pragma unroll
    for (int nt = 0; nt < 3; ++nt)
#pragma unroll
      for (int ks = 0; ks < 2; ++ks)
        bx[nt][ks] = lds_ld8(sm + UO + (c + 16 * nt) * 72 + 8 * q + 32 * ks);
    f32x4 acc[8][3];
#pragma unroll
    for (int mt = 0; mt < 8; ++mt)
#pragma unroll
      for (int nt = 0; nt < 3; ++nt) acc[mt][nt] = z4;
#pragma unroll
    for (int mt = 0; mt < 8; ++mt) {
      bf16x8 a0 = *reinterpret_cast<const bf16x8*>(Wg + (c + 16 * mt) * 64 + 8 * q);
      bf16x8 a1 = *reinterpret_cast<const bf16x8*>(Wg + (c + 16 * mt) * 64 + 8 * q + 32);
#pragma unroll
      for (int nt = 0; nt < 3; ++nt) {
        acc[mt][nt] = mfma16(a0, bx[nt][0], acc[mt][nt]);
        acc[mt][nt] = mfma16(a1, bx[nt][1], acc[mt][nt]);
      }
    }
    const int dstO = (w == 0) ? QO : (w == 1) ? KO : RO;
#pragma unroll
    for (int mt = 0; mt < 8; ++mt) {
      float4 bb = *reinterpret_cast<const float4*>(bias + 16 * mt + 4 * q);
#pragma unroll
      for (int nt = 0; nt < 3; ++nt) {
        int f = c + 16 * nt;
        if (f < 40) {                                        // keep rows 40..47 out of neighbors
          uint2 pk;
          pk.x = pk2(acc[mt][nt][0] + bb.x, acc[mt][nt][1] + bb.y);
          pk.y = pk2(acc[mt][nt][2] + bb.z, acc[mt][nt][3] + bb.w);
          *reinterpret_cast<uint2*>(sm + dstO + f * 136 + 16 * mt + 4 * q) = pk;
        }
      }
    }
  } else {
    // V: D[f][o] = sum_e x[f][e] * W[o][e] -> store transposed Vt[o][f]
    bf16x8 ax[3][2];
#pragma unroll
    for (int mt = 0; mt < 3; ++mt)
#pragma unroll
      for (int ks = 0; ks < 2; ++ks)
        ax[mt][ks] = lds_ld8(sm + UO + (c + 16 * mt) * 72 + 8 * q + 32 * ks);
    f32x4 acc[3][8];
#pragma unroll
    for (int mt = 0; mt < 3; ++mt)
#pragma unroll
      for (int nt = 0; nt < 8; ++nt) acc[mt][nt] = z4;
#pragma unroll
    for (int nt = 0; nt < 8; ++nt) {
      bf16x8 b0 = *reinterpret_cast<const bf16x8*>(Wg + (c + 16 * nt) * 64 + 8 * q);
      bf16x8 b1 = *reinterpret_cast<const bf16x8*>(Wg + (c + 16 * nt) * 64 + 8 * q + 32);
#pragma unroll
      for (int mt = 0; mt < 3; ++mt) {
        acc[mt][nt] = mfma16(ax[mt][0], b0, acc[mt][nt]);
        acc[mt][nt] = mfma16(ax[mt][1], b1, acc[mt][nt]);
      }
    }
#pragma unroll
    for (int nt = 0; nt < 8; ++nt) {
      float bb = bias[c + 16 * nt];
#pragma unroll
      for (int mt = 0; mt < 3; ++mt) {
        uint2 pk;
        pk.x = pk2(acc[mt][nt][0] + bb, acc[mt][nt][1] + bb);
        pk.y = pk2(acc[mt][nt][2] + bb, acc[mt][nt][3] + bb);
        *reinterpret_cast<uint2*>(sm + VO + (c + 16 * nt) * 72 + 16 * mt + 4 * q) = pk;
      }
    }
  }
  __syncthreads();

  // ---------- Phase C: S^T = K Q^T (head w), softmax over g (rows), P[f][g] ----------
  unsigned short* pb = sm + UO + w * PSZ;
  {
    bf16x8 ka[3], qb[3];
#pragma unroll
    for (int gt = 0; gt < 3; ++gt)
      ka[gt] = lds_ld8(sm + KO + (c + 16 * gt) * 136 + 32 * w + 8 * q);
#pragma unroll
    for (int ft = 0; ft < 3; ++ft)
      qb[ft] = lds_ld8(sm + QO + (c + 16 * ft) * 136 + 32 * w + 8 * q);
    f32x4 s[3][3];
#pragma unroll
    for (int gt = 0; gt < 3; ++gt)
#pragma unroll
      for (int ft = 0; ft < 3; ++ft)
        s[gt][ft] = mfma16(ka[gt], qb[ft], z4);              // row=g(=4q+r+16gt), col=f
    const float cexp = 0.125f * 1.44269504f;                 // scale(1/sqrt64) * log2(e)
#pragma unroll
    for (int ft = 0; ft < 3; ++ft) {
      int f = c + 16 * ft;
      float m = -1e30f;
#pragma unroll
      for (int gt = 0; gt < 2; ++gt)
#pragma unroll
        for (int r = 0; r < 4; ++r) m = fmaxf(m, s[gt][ft][r]);
      if (q < 2) {                                           // gt=2 valid only for g<40
#pragma unroll
        for (int r = 0; r < 4; ++r) m = fmaxf(m, s[2][ft][r]);
      }
      m = fmaxf(m, __shfl_xor(m, 16, 64));
      m = fmaxf(m, __shfl_xor(m, 32, 64));
      float p[3][4]; float sum = 0.f;
#pragma unroll
      for (int gt = 0; gt < 3; ++gt)
#pragma unroll
        for (int r = 0; r < 4; ++r) {
          float pe = EXP2F((s[gt][ft][r] - m) * cexp);
          if (gt == 2 && q >= 2) pe = 0.f;                   // mask g = 40..47
          p[gt][r] = pe; sum += pe;
        }
      sum += __shfl_xor(sum, 16, 64);
      sum += __shfl_xor(sum, 32, 64);
      float inv = RCPF(sum);
      if (f < 40) {                                          // don't spill into neighbor P
#pragma unroll
        for (int gt = 0; gt < 3; ++gt) {
          uint2 pk;
          pk.x = pk2(p[gt][0] * inv, p[gt][1] * inv);
          pk.y = pk2(p[gt][2] * inv, p[gt][3] * inv);
          *reinterpret_cast<uint2*>(pb + f * 72 + 16 * gt + 4 * q) = pk;
        }
      }
    }
    uint2 zz; zz.x = 0; zz.y = 0;                            // P[0..39][48..63] = 0
    for (int i = l; i < 160; i += 64) {
      int r = i >> 2, j = i & 3;
      *reinterpret_cast<uint2*>(pb + r * 72 + 48 + 4 * j) = zz;
    }
  }

  // ---------- Phase D: O = P V (same-wave LDS, no barrier needed) ----------
  f32x4 o[3][2];
  {
    bf16x8 pa[3][2], vb[2][2];
#pragma unroll
    for (int mt = 0; mt < 3; ++mt)
#pragma unroll
      for (int ks = 0; ks < 2; ++ks)
        pa[mt][ks] = lds_ld8(pb + (c + 16 * mt) * 72 + 8 * q + 32 * ks);
#pragma unroll
    for (int nt = 0; nt < 2; ++nt)
#pragma unroll
      for (int ks = 0; ks < 2; ++ks)
        vb[nt][ks] = lds_ld8(sm + VO + (32 * w + c + 16 * nt) * 72 + 8 * q + 32 * ks);
#pragma unroll
    for (int mt = 0; mt < 3; ++mt)
#pragma unroll
      for (int nt = 0; nt < 2; ++nt) {
        f32x4 a = z4;
        a = mfma16(pa[mt][0], vb[nt][0], a);
        a = mfma16(pa[mt][1], vb[nt][1], a);
        o[mt][nt] = a;
      }
  }

  // ---------- Phase E: epilogue relu(O + R) ----------
  {
    float* ob = out + (size_t)b * (F_DIM * O_DIM) + 32 * w;
#pragma unroll
    for (int mt = 0; mt < 3; ++mt) {
      int f0 = 16 * mt + 4 * q;
      if (f0 < 40) {
#pragma unroll
        for (int nt = 0; nt < 2; ++nt) {
          int col = c + 16 * nt;
#pragma unroll
          for (int r = 0; r < 4; ++r) {
            float rv = bf2f(sm[RO + (f0 + r) * 136 + 32 * w + col]);
            float val = o[mt][nt][r] + rv;
            ob[(size_t)(f0 + r) * O_DIM + col] = fmaxf(val, 0.f);
          }
        }
      }
    }
  }
}

extern "C" void kernel_launch(void* const* d_in, const int* in_sizes, int n_in,
                              void* d_out, int out_size, void* d_ws, size_t ws_size,
                              hipStream_t stream) {
  const float* x  = (const float*)d_in[0];
  const float* Wq = (const float*)d_in[1];
  const float* bq = (const float*)d_in[2];
  const float* Wk = (const float*)d_in[3];
  const float* bk = (const float*)d_in[4];
  const float* Wv = (const float*)d_in[5];
  const float* bv = (const float*)d_in[6];
  const float* Wr = (const float*)d_in[7];
  const float* br = (const float*)d_in[8];
  unsigned short* wbf = (unsigned short*)d_ws;               // 32768 bf16 = 64 KB
  float* out = (float*)d_out;
  convert_weights<<<128, 256, 0, stream>>>(Wq, Wk, Wv, Wr, wbf);
  interact_kernel<<<16384, 256, 0, stream>>>(x, wbf, bq, bk, bv, br, out);
}

// Round 2
// 597.918 us; speedup vs baseline: 1.1355x; 1.1355x over previous
//
#include <hip/hip_runtime.h>
#include <hip/hip_bf16.h>

// InteractingLayer: B=16384, F=40, E=64, H=4, D=32, OUT=128
// One block (256 thr, 4 waves) per batch element. Wave w owns head w
// END-TO-END: computes Q/K/V/R column-slices [32w,32w+32) itself, then does
// head-w attention. Only x-staging is shared -> ONE barrier, waves free-run.
// P (softmax probs) never touches LDS: C-layout -> A-operand transform is a
// quad-redistribution at fixed lane-column, done with __shfl.

#define F_DIM 40
#define O_DIM 128

typedef __bf16 bf16x8 __attribute__((ext_vector_type(8)));
typedef float  f32x4  __attribute__((ext_vector_type(4)));

// ---- LDS map (ushort units) ----
// xb [48][72] @ 0 (3456)  shared x staging (bf16), rows 40..47 zeroed
// per head h @ 3456 + h*5504  (wave-private):
//   Q  [40][40] @ +0     rows 40..47 spill-read into K (finite bf16, masked)
//   K  [40][40] @ +1600  rows 40..47 spill-read into Vt (finite, masked)
//   Vt [32][72] @ +3200  cols 48..63 zeroed; 64..71 pad (never read by PV)
// Q+K region reused as fp32 out-stage [40][40] in epilogue (same wave only).
#define XBS 72
#define QS  40
#define VTS 72
#define HB0 3456
#define HSZ 5504
#define TOT 25472   // ushorts = 50944 B -> 3 blocks/CU, __launch_bounds__(256,3)

static __device__ __forceinline__ unsigned short f2bf(float f) {
  unsigned u = __builtin_bit_cast(unsigned, f);
  u += 0x7FFFu + ((u >> 16) & 1u);          // RNE
  return (unsigned short)(u >> 16);
}
static __device__ __forceinline__ float bf2f(unsigned short h) {
  unsigned u = ((unsigned)h) << 16;
  return __builtin_bit_cast(float, u);
}
static __device__ __forceinline__ unsigned pk2(float a, float b) {
  return (unsigned)f2bf(a) | ((unsigned)f2bf(b) << 16);
}
union V8 { uint2 u2[2]; uint4 u4; unsigned u[4]; bf16x8 v; };
static __device__ __forceinline__ bf16x8 lds_ld8(const unsigned short* p) {   // 8B-aligned
  V8 t; t.u2[0] = *(const uint2*)p; t.u2[1] = *(const uint2*)(p + 4); return t.v;
}
static __device__ __forceinline__ bf16x8 lds_ld16(const unsigned short* p) {  // 16B-aligned
  V8 t; t.u4 = *(const uint4*)p; return t.v;
}
static __device__ __forceinline__ f32x4 mfma16(bf16x8 a, bf16x8 b, f32x4 c) {
  return __builtin_amdgcn_mfma_f32_16x16x32_bf16(a, b, c, 0, 0, 0);
}

#if __has_builtin(__builtin_amdgcn_exp2f)
#define EXP2F __builtin_amdgcn_exp2f
#else
#define EXP2F exp2f
#endif
#if __has_builtin(__builtin_amdgcn_rcpf)
#define RCPF __builtin_amdgcn_rcpf
#else
#define RCPF(x) (1.0f / (x))
#endif

__global__ void convert_weights(const float* __restrict__ Wq, const float* __restrict__ Wk,
                                const float* __restrict__ Wv, const float* __restrict__ Wr,
                                unsigned short* __restrict__ ws) {
  int i = blockIdx.x * 256 + threadIdx.x;   // 0..32767
  const float* src = (i < 8192) ? Wq : (i < 16384) ? Wk : (i < 24576) ? Wv : Wr;
  ws[i] = f2bf(src[i & 8191]);
}

__global__ __launch_bounds__(256, 3) void interact_kernel(
    const float* __restrict__ x, const unsigned short* __restrict__ wbf,
    const float* __restrict__ bq, const float* __restrict__ bk,
    const float* __restrict__ bv, const float* __restrict__ br,
    float* __restrict__ out) {
  __shared__ __align__(16) unsigned short sm[TOT];
  const int t = threadIdx.x;
  const int w = t >> 6;        // wave = head
  const int l = t & 63;
  const int c = l & 15;        // MFMA lane-column
  const int q = l >> 4;        // quad
  const int b = blockIdx.x;
  f32x4 z4 = {0.f, 0.f, 0.f, 0.f};

  // ---------- Phase A: stage x -> LDS bf16 (shared); zero pad rows ----------
  const float* xp = x + (size_t)b * (F_DIM * 64);
  for (int i = t; i < 640; i += 256) {                       // 640 float4 = 40x64
    float4 v4 = reinterpret_cast<const float4*>(xp)[i];
    int f = i >> 4, e4 = (i & 15) << 2;
    uint2 pk; pk.x = pk2(v4.x, v4.y); pk.y = pk2(v4.z, v4.w);
    *reinterpret_cast<uint2*>(sm + f * XBS + e4) = pk;
  }
  {
    uint2 z; z.x = 0; z.y = 0;
    for (int i = t; i < 144; i += 256)                       // rows 40..47 = 0
      reinterpret_cast<uint2*>(sm + 40 * XBS)[i] = z;
  }
  __syncthreads();                                           // the only barrier

  const int hb = HB0 + w * HSZ;
  unsigned short* Qb  = sm + hb;
  unsigned short* Kb  = Qb + 1600;
  unsigned short* Vtb = Qb + 3200;

  // x fragments: rows f=c+16t, k=e in quads. Serves as A- and B-operand.
  bf16x8 xf[3][2];
#pragma unroll
  for (int nt = 0; nt < 3; ++nt)
#pragma unroll
    for (int ks = 0; ks < 2; ++ks)
      xf[nt][ks] = lds_ld8(sm + (c + 16 * nt) * XBS + 32 * ks + 8 * q);

  // ---------- Phase B: per-head projections ----------
  // Q,K: D[d][f] (A=W rows d, B=x rows f); store [f][d] with contiguous uint2
  {
    const unsigned short* Wm[2] = { wbf + 32 * w * 64, wbf + 8192 + 32 * w * 64 };
    const float* Bp[2] = { bq, bk };
    unsigned short* Db[2] = { Qb, Kb };
#pragma unroll
    for (int pr = 0; pr < 2; ++pr) {
#pragma unroll
      for (int mt = 0; mt < 2; ++mt) {
        const unsigned short* wr0 = Wm[pr] + (16 * mt + c) * 64 + 8 * q;
        bf16x8 a0 = *reinterpret_cast<const bf16x8*>(wr0);
        bf16x8 a1 = *reinterpret_cast<const bf16x8*>(wr0 + 32);
        float4 bb = *reinterpret_cast<const float4*>(Bp[pr] + 32 * w + 16 * mt + 4 * q);
#pragma unroll
        for (int nt = 0; nt < 3; ++nt) {
          f32x4 acc = mfma16(a1, xf[nt][1], mfma16(a0, xf[nt][0], z4));
          int f = c + 16 * nt;
          if (f < 40) {
            uint2 pk;
            pk.x = pk2(acc[0] + bb.x, acc[1] + bb.y);
            pk.y = pk2(acc[2] + bb.z, acc[3] + bb.w);
            *reinterpret_cast<uint2*>(Db[pr] + f * QS + 16 * mt + 4 * q) = pk;
          }
        }
      }
    }
  }
  // V: D[f][d] (A=x rows f, B=W rows d); store transposed Vt[d][f]
#pragma unroll
  for (int nt = 0; nt < 2; ++nt) {
    const unsigned short* wr0 = wbf + 2 * 8192 + (32 * w + 16 * nt + c) * 64 + 8 * q;
    bf16x8 b0 = *reinterpret_cast<const bf16x8*>(wr0);
    bf16x8 b1 = *reinterpret_cast<const bf16x8*>(wr0 + 32);
    float bb = bv[32 * w + c + 16 * nt];
#pragma unroll
    for (int mt = 0; mt < 3; ++mt) {
      f32x4 acc = mfma16(xf[mt][1], b1, mfma16(xf[mt][0], b0, z4));
      uint2 pk;
      pk.x = pk2(acc[0] + bb, acc[1] + bb);
      pk.y = pk2(acc[2] + bb, acc[3] + bb);
      *reinterpret_cast<uint2*>(Vtb + (c + 16 * nt) * VTS + 16 * mt + 4 * q) = pk;
    }
  }
  {
    uint2 zz; zz.x = 0; zz.y = 0;                            // Vt[:,48..63] = 0
#pragma unroll
    for (int k2 = 0; k2 < 2; ++k2) {
      int idx = l + 64 * k2, row = idx >> 2, g4 = idx & 3;
      *reinterpret_cast<uint2*>(Vtb + row * VTS + 48 + 4 * g4) = zz;
    }
  }
  // R: D[f][d] — same layout as O; keep packed in registers
  unsigned rp[3][2][2];
#pragma unroll
  for (int nt = 0; nt < 2; ++nt) {
    const unsigned short* wr0 = wbf + 3 * 8192 + (32 * w + 16 * nt + c) * 64 + 8 * q;
    bf16x8 b0 = *reinterpret_cast<const bf16x8*>(wr0);
    bf16x8 b1 = *reinterpret_cast<const bf16x8*>(wr0 + 32);
#pragma unroll
    for (int mt = 0; mt < 3; ++mt) {
      f32x4 acc = mfma16(xf[mt][1], b1, mfma16(xf[mt][0], b0, z4));
      rp[mt][nt][0] = pk2(acc[0], acc[1]);
      rp[mt][nt][1] = pk2(acc[2], acc[3]);
    }
  }

  // ---------- Phase C: S^T = K Q^T, softmax over g (rows) ----------
  f32x4 s[3][3];
  {
    bf16x8 kf[3], qf[3];
#pragma unroll
    for (int gt = 0; gt < 3; ++gt) kf[gt] = lds_ld16(Kb + (c + 16 * gt) * QS + 8 * q);
#pragma unroll
    for (int ft = 0; ft < 3; ++ft) qf[ft] = lds_ld16(Qb + (c + 16 * ft) * QS + 8 * q);
#pragma unroll
    for (int gt = 0; gt < 3; ++gt)
#pragma unroll
      for (int ft = 0; ft < 3; ++ft)
        s[gt][ft] = mfma16(kf[gt], qf[ft], z4);              // row g=16gt+4q+r, col f
  }
  unsigned pp[3][3][2];                                      // [ft][gt][pair]
  const float cexp = 0.125f * 1.44269504f;                   // 1/sqrt(64) * log2(e)
#pragma unroll
  for (int ft = 0; ft < 3; ++ft) {
    float m = -1e30f;
#pragma unroll
    for (int gt = 0; gt < 2; ++gt)
#pragma unroll
      for (int r = 0; r < 4; ++r) m = fmaxf(m, s[gt][ft][r]);
    if (q < 2) {
#pragma unroll
      for (int r = 0; r < 4; ++r) m = fmaxf(m, s[2][ft][r]);
    }
    m = fmaxf(m, __shfl_xor(m, 16, 64));
    m = fmaxf(m, __shfl_xor(m, 32, 64));
    float p[3][4]; float sum = 0.f;
#pragma unroll
    for (int gt = 0; gt < 3; ++gt)
#pragma unroll
      for (int r = 0; r < 4; ++r) {
        float pe = EXP2F((s[gt][ft][r] - m) * cexp);
        if (gt == 2 && q >= 2) pe = 0.f;                     // mask g=40..47
        p[gt][r] = pe; sum += pe;
      }
    sum += __shfl_xor(sum, 16, 64);
    sum += __shfl_xor(sum, 32, 64);
    float inv = RCPF(sum);
#pragma unroll
    for (int gt = 0; gt < 3; ++gt) {
      pp[ft][gt][0] = pk2(p[gt][0] * inv, p[gt][1] * inv);
      pp[ft][gt][1] = pk2(p[gt][2] * inv, p[gt][3] * inv);
    }
  }

  // ---------- P: C-layout -> A-operand via quad shuffles (no LDS) ----------
  // target elem pair (j=2a,2a+1), g=32ks+8q+2a: src lane c+16*((2q+(a>>1))&3),
  // src reg gt'=2ks+(q>>1), pair a&1. g in [40,48): genuine zeros; [48,64): 0.
  bf16x8 pf[3][2];
#pragma unroll
  for (int mt = 0; mt < 3; ++mt) {
    V8 f0, f1;
#pragma unroll
    for (int a = 0; a < 4; ++a) {
      int src = 16 * ((2 * q + (a >> 1)) & 3) + c;
      unsigned v0 = (unsigned)__shfl((int)pp[mt][0][a & 1], src, 64);
      unsigned v1 = (unsigned)__shfl((int)pp[mt][1][a & 1], src, 64);
      unsigned v2 = (unsigned)__shfl((int)pp[mt][2][a & 1], src, 64);
      f0.u[a] = (q < 2) ? v0 : v1;                           // ks=0: gt'=q>>1
      f1.u[a] = (q < 2) ? v2 : 0u;                           // ks=1: gt'=2 or zero
    }
    pf[mt][0] = f0.v; pf[mt][1] = f1.v;
  }

  // ---------- Phase D: O = P V ----------
  f32x4 o[3][2];
  {
    bf16x8 vb[2][2];
#pragma unroll
    for (int nt = 0; nt < 2; ++nt)
#pragma unroll
      for (int ks = 0; ks < 2; ++ks)
        vb[nt][ks] = lds_ld16(Vtb + (c + 16 * nt) * VTS + 32 * ks + 8 * q);
#pragma unroll
    for (int mt = 0; mt < 3; ++mt)
#pragma unroll
      for (int nt = 0; nt < 2; ++nt)
        o[mt][nt] = mfma16(pf[mt][1], vb[nt][1], mfma16(pf[mt][0], vb[nt][0], z4));
  }

  // ---------- Phase E: relu(O + R) -> stage fp32 in Q/K region -> float4 out ----------
  float* os = reinterpret_cast<float*>(sm + hb);             // [40][40] fp32, wave-private
  float brv0 = br[32 * w + c], brv1 = br[32 * w + c + 16];
#pragma unroll
  for (int mt = 0; mt < 3; ++mt) {
    if (mt < 2 || q < 2) {
#pragma unroll
      for (int nt = 0; nt < 2; ++nt) {
        float bb = nt ? brv1 : brv0;
#pragma unroll
        for (int r = 0; r < 4; ++r) {
          int f = 16 * mt + 4 * q + r;
          unsigned pr_ = rp[mt][nt][r >> 1];
          float rv = bf2f((unsigned short)((r & 1) ? (pr_ >> 16) : (pr_ & 0xFFFFu)));
          os[f * QS + c + 16 * nt] = fmaxf(o[mt][nt][r] + rv + bb, 0.f);
        }
      }
    }
  }
  float* op = out + (size_t)b * (F_DIM * O_DIM) + 32 * w;
#pragma unroll
  for (int it = 0; it < 5; ++it) {
    int i = 64 * it + l;
    int f = i >> 3, d4 = i & 7;
    float4 v = *reinterpret_cast<const float4*>(os + f * QS + 4 * d4);
    *reinterpret_cast<float4*>(op + (size_t)f * O_DIM + 4 * d4) = v;
  }
}

extern "C" void kernel_launch(void* const* d_in, const int* in_sizes, int n_in,
                              void* d_out, int out_size, void* d_ws, size_t ws_size,
                              hipStream_t stream) {
  const float* x  = (const float*)d_in[0];
  const float* Wq = (const float*)d_in[1];
  const float* bq = (const float*)d_in[2];
  const float* Wk = (const float*)d_in[3];
  const float* bk = (const float*)d_in[4];
  const float* Wv = (const float*)d_in[5];
  const float* bv = (const float*)d_in[6];
  const float* Wr = (const float*)d_in[7];
  const float* br = (const float*)d_in[8];
  unsigned short* wbf = (unsigned short*)d_ws;               // 32768 bf16 = 64 KB
  float* out = (float*)d_out;
  convert_weights<<<128, 256, 0, stream>>>(Wq, Wk, Wv, Wr, wbf);
  interact_kernel<<<16384, 256, 0, stream>>>(x, wbf, bq, bk, bv, br, out);
}